// Round 1
// baseline (3982.390 us; speedup 1.0000x reference)
//
#include <hip/hip_runtime.h>
#include <stdint.h>
#include <math.h>

#define N_ROWS 8192
#define N_TOK  8192
#define N_DIM  512
#define N_SAMP 10
#define GK     1536   // 3 * 512, bf16x2 split zones

typedef __attribute__((ext_vector_type(8))) short bf16x8_t;
typedef __attribute__((ext_vector_type(4))) float f32x4_t;

// ---------------- JAX threefry2x32 (exact) ----------------
__host__ __device__ __forceinline__ void tf2x32(uint32_t ks0, uint32_t ks1,
                                                uint32_t& x0, uint32_t& x1) {
  uint32_t ks2 = ks0 ^ ks1 ^ 0x1BD11BDAu;
  x0 += ks0; x1 += ks1;
#define TF_ROUND(r) { x0 += x1; x1 = (x1 << (r)) | (x1 >> (32 - (r))); x1 ^= x0; }
  TF_ROUND(13) TF_ROUND(15) TF_ROUND(26) TF_ROUND(6)
  x0 += ks1; x1 += ks2 + 1u;
  TF_ROUND(17) TF_ROUND(29) TF_ROUND(16) TF_ROUND(24)
  x0 += ks2; x1 += ks0 + 2u;
  TF_ROUND(13) TF_ROUND(15) TF_ROUND(26) TF_ROUND(6)
  x0 += ks0; x1 += ks1 + 3u;
  TF_ROUND(17) TF_ROUND(29) TF_ROUND(16) TF_ROUND(24)
  x0 += ks1; x1 += ks2 + 4u;
  TF_ROUND(13) TF_ROUND(15) TF_ROUND(26) TF_ROUND(6)
  x0 += ks2; x1 += ks0 + 5u;
#undef TF_ROUND
}

__device__ __forceinline__ unsigned short f2bf_rne(float f) {
  uint32_t u = __float_as_uint(f);
  uint32_t r = (u + 0x7fffu + ((u >> 16) & 1u)) >> 16;
  return (unsigned short)r;
}
__device__ __forceinline__ float bf2f(unsigned short h) {
  return __uint_as_float((uint32_t)h << 16);
}

__device__ __forceinline__ unsigned long long shfl_xor_u64(unsigned long long v, int off) {
  uint32_t lo = (uint32_t)v, hi = (uint32_t)(v >> 32);
  lo = (uint32_t)__shfl_xor((int)lo, off, 64);
  hi = (uint32_t)__shfl_xor((int)hi, off, 64);
  return ((unsigned long long)hi << 32) | lo;
}

// ---------------- row sum-of-squares ----------------
__global__ __launch_bounds__(256) void rownorm_kernel(const float* __restrict__ M,
                                                      float* __restrict__ out) {
  int lane = threadIdx.x & 63;
  int row = (int)((blockIdx.x * blockDim.x + threadIdx.x) >> 6);
  const float* p = M + (size_t)row * N_DIM;
  float acc = 0.f;
#pragma unroll
  for (int d = 0; d < N_DIM; d += 64) {
    float v = p[d + lane];
    acc = fmaf(v, v, acc);
  }
#pragma unroll
  for (int off = 32; off; off >>= 1) acc += __shfl_xor(acc, off, 64);
  if (lane == 0) out[row] = acc;
}

// ---------------- state init ----------------
__global__ __launch_bounds__(256) void init_champ_kernel(unsigned long long* __restrict__ c) {
  int i = blockIdx.x * 256 + threadIdx.x;
  if (i < N_ROWS * N_SAMP) c[i] = 0xFFFFFFFFFFFFFFFFULL;
}

__global__ __launch_bounds__(256) void init_state_kernel(float* __restrict__ rmin,
                                                         int* __restrict__ ridx) {
  int i = blockIdx.x * 256 + threadIdx.x;
  if (i < N_ROWS * N_SAMP) { rmin[i] = INFINITY; ridx[i] = 0; }
}

// ---------------- bf16x2 split ----------------
__global__ __launch_bounds__(256) void split_kernel(const float* __restrict__ src,
                                                    unsigned short* __restrict__ dst,
                                                    int mode) {
  int t = blockIdx.x * 256 + threadIdx.x;
  int row = t >> 7;
  int c = (t & 127) << 2;
  float4 v = *(const float4*)(src + (size_t)row * N_DIM + c);
  ushort4 hi, lo;
  hi.x = f2bf_rne(v.x); lo.x = f2bf_rne(v.x - bf2f(hi.x));
  hi.y = f2bf_rne(v.y); lo.y = f2bf_rne(v.y - bf2f(hi.y));
  hi.z = f2bf_rne(v.z); lo.z = f2bf_rne(v.z - bf2f(hi.z));
  hi.w = f2bf_rne(v.w); lo.w = f2bf_rne(v.w - bf2f(hi.w));
  unsigned short* base = dst + (size_t)row * GK;
  *(ushort4*)(base + c) = hi;
  if (mode == 0) {
    *(ushort4*)(base + 512 + c) = lo;
    *(ushort4*)(base + 1024 + c) = hi;
  } else {
    *(ushort4*)(base + 512 + c) = hi;
    *(ushort4*)(base + 1024 + c) = lo;
  }
}

__device__ __forceinline__ void async_cp16(const void* g, void* l) {
  __builtin_amdgcn_global_load_lds((const __attribute__((address_space(1))) void*)g,
                                   (__attribute__((address_space(3))) void*)l, 16, 0, 0);
}

// ---------------- FUSED bf16 MFMA GEMM + multinomial sampler ----------------
// GEMM part is bit-identical to the proven gemm_bf16_kernel (same staging swizzle,
// same fragment order, same MFMA sequence). Epilogue: instead of E=expf(dist) to
// HBM + separate VALU-bound sample pass, run threefry/screen/Gumbel on the 64
// register-resident distances and publish via packed-u64 atomicMin:
//   pack = (f32bits(wv)<<32) | k   (min == min wv, ties -> min k; same as serial)
// Screen threshold is a per-block snapshot of the global champion: stale values
// are only ever LARGER (champ decreases monotonically) -> screen is strictly
// conservative -> final atomicMin result exact and order-independent.
__global__ __launch_bounds__(256) void fused_gemm_sample_kernel(
    const unsigned short* __restrict__ A2, const unsigned short* __restrict__ B2,
    const float* __restrict__ xx, const float* __restrict__ ee,
    unsigned long long* __restrict__ champ, uint32_t k0, uint32_t k1) {
  __shared__ __align__(16) unsigned short As[128 * 64];
  __shared__ __align__(16) unsigned short Bs[128 * 64];
  __shared__ uint32_t thr[128 * N_SAMP];
  int tid = threadIdx.x;
  int w = tid >> 6, l = tid & 63;

  // banded swizzle: 64 consecutive bids cover an 8x8 supertile (~6 MB hot set).
  int gx = gridDim.x;
  int bid = blockIdx.y * gx + blockIdx.x;
  int band = bid / (8 * gx);
  int t8 = bid % (8 * gx);
  int by = band * 8 + (t8 & 7);
  int bx = t8 >> 3;

  int row0 = by * 128;
  int col0 = bx * 128;
  int wm = (w & 1) * 64, wn = (w >> 1) * 64;
  int quad = l >> 4, r15 = l & 15;

  f32x4_t acc[4][4];
#pragma unroll
  for (int i = 0; i < 4; ++i)
#pragma unroll
    for (int j = 0; j < 4; ++j) acc[i][j] = (f32x4_t){0.f, 0.f, 0.f, 0.f};

  int srow[4], skc[4];
#pragma unroll
  for (int r = 0; r < 4; ++r) {
    int c = tid + 256 * r;
    srow[r] = c >> 3;
    skc[r] = (c & 7) ^ (srow[r] & 7);
  }

  for (int kt = 0; kt < GK; kt += 64) {
#pragma unroll
    for (int r = 0; r < 4; ++r) {
      int c = tid + 256 * r;
      async_cp16(A2 + (size_t)(row0 + srow[r]) * GK + kt + skc[r] * 8, As + c * 8);
      async_cp16(B2 + (size_t)(col0 + srow[r]) * GK + kt + skc[r] * 8, Bs + c * 8);
    }
    __syncthreads();

#pragma unroll
    for (int kk2 = 0; kk2 < 2; ++kk2) {
      bf16x8_t af[4], bf[4];
#pragma unroll
      for (int i = 0; i < 4; ++i) {
        int row = wm + i * 16 + r15;
        int qc = (kk2 * 4 + quad) ^ (r15 & 7);
        af[i] = *(const bf16x8_t*)&As[row * 64 + qc * 8];
      }
#pragma unroll
      for (int j = 0; j < 4; ++j) {
        int row = wn + j * 16 + r15;
        int qc = (kk2 * 4 + quad) ^ (r15 & 7);
        bf[j] = *(const bf16x8_t*)&Bs[row * 64 + qc * 8];
      }
#pragma unroll
      for (int i = 0; i < 4; ++i)
#pragma unroll
        for (int j = 0; j < 4; ++j)
          acc[i][j] = __builtin_amdgcn_mfma_f32_16x16x32_bf16(af[i], bf[j], acc[i][j], 0, 0, 0);
    }
    __syncthreads();
  }

  // ---- snapshot screen thresholds for this block's 128 rows (fresh as possible) ----
#pragma unroll 1
  for (int t = tid; t < 128 * N_SAMP; t += 256) {
    int rl = t / N_SAMP;
    int s = t - rl * N_SAMP;
    unsigned long long c = champ[(size_t)(row0 + rl) * N_SAMP + s];
    uint32_t hi = (uint32_t)(c >> 32);
    uint32_t th = 0u;
    if (hi < 0x7F800000u) {  // finite champion exists
      float ut = expf(-__uint_as_float(hi)) * 0.999999f;  // conservative (Ek>=1)
      th = ((uint32_t)(ut * 8388608.0f)) << 9;
    }
    thr[t] = th;
  }
  __syncthreads();

  // ---- sampling epilogue on register-resident distances ----
  const float inv_nt = 1.f / 8192.f;
  const float tiny = 1.1754943508222875e-38f;
  float eev[4];
#pragma unroll
  for (int j = 0; j < 4; ++j) eev[j] = ee[col0 + wn + j * 16 + r15];
  int cb = col0 + wn + r15;  // + j*16 per fragment column

#pragma unroll
  for (int i = 0; i < 4; ++i) {
#pragma unroll
    for (int r = 0; r < 4; ++r) {
      int lrow = wm + i * 16 + quad * 4 + r;
      int grow = row0 + lrow;
      float xxv = xx[grow];
      float dist[4];
#pragma unroll
      for (int j = 0; j < 4; ++j)
        dist[j] = (xxv + eev[j] - 2.0f * acc[i][j][r]) * inv_nt;
      uint32_t row_c = (uint32_t)grow * 81920u;
#pragma unroll 1
      for (int s = 0; s < N_SAMP; ++s) {
        uint32_t th = thr[lrow * N_SAMP + s];          // LDS broadcast in 16-group
        uint32_t sb = row_c + (uint32_t)s * 8192u;
        unsigned long long ch = 0xFFFFFFFFFFFFFFFFULL;
#pragma unroll
        for (int j = 0; j < 4; ++j) {
          uint32_t kk = (uint32_t)(cb + j * 16);
          uint32_t x0 = 0u, x1 = sb + kk;
          tf2x32(k0, k1, x0, x1);
          uint32_t bits = x0 ^ x1;
          if (bits >= th) {
            float u = __uint_as_float(0x3f800000u | (bits >> 9)) - 1.0f;
            u = fmaxf(u, tiny);
            float wv = -logf(u) * expf(dist[j]);       // exact r6 arithmetic
            unsigned long long p = ((unsigned long long)__float_as_uint(wv) << 32) | kk;
            if (p < ch) ch = p;
          }
        }
        // skip the 16-lane reduce unless some lane in this row-group has a candidate
        unsigned long long ball = __ballot(ch != 0xFFFFFFFFFFFFFFFFULL);
        if ((ball >> (quad << 4)) & 0xFFFFULL) {
#pragma unroll
          for (int off = 1; off < 16; off <<= 1) {
            unsigned long long op = shfl_xor_u64(ch, off);
            if (op < ch) ch = op;
          }
          if (r15 == 0) {
            unsigned long long* cp = champ + (size_t)grow * N_SAMP + s;
            if (ch < *cp) atomicMin(cp, ch);           // stale read only delays, never wrong
          }
        }
      }
    }
  }
}

// ---------------- fp32 NT GEMM (fallback, r6-proven) with E-epilogue ----------------
__global__ __launch_bounds__(256) void gemm_nt_kernel(const float* __restrict__ A,
                                                      const float* __restrict__ B,
                                                      const float* __restrict__ xx,
                                                      const float* __restrict__ ee,
                                                      float* __restrict__ E,
                                                      int ks, int KC) {
  __shared__ __align__(16) float Asf[32][68];
  __shared__ __align__(16) float Bsf[32][68];
  int tid = threadIdx.x;
  int row0 = blockIdx.y * 64;
  int colB0 = blockIdx.x * 64 + ks;
  int tx = tid & 15, ty = tid >> 4;
  float acc[4][4] = {};
  for (int d0 = 0; d0 < N_DIM; d0 += 32) {
#pragma unroll
    for (int r = 0; r < 2; ++r) {
      int c = tid + 256 * r;
      int m = c >> 3;
      int dv = (c & 7) << 2;
      const float4 va = *(const float4*)(A + (size_t)(row0 + m) * N_DIM + d0 + dv);
      Asf[dv + 0][m] = va.x; Asf[dv + 1][m] = va.y;
      Asf[dv + 2][m] = va.z; Asf[dv + 3][m] = va.w;
      const float4 vb = *(const float4*)(B + (size_t)(colB0 + m) * N_DIM + d0 + dv);
      Bsf[dv + 0][m] = vb.x; Bsf[dv + 1][m] = vb.y;
      Bsf[dv + 2][m] = vb.z; Bsf[dv + 3][m] = vb.w;
    }
    __syncthreads();
#pragma unroll
    for (int dd = 0; dd < 32; ++dd) {
      float4 a4 = *(const float4*)&Asf[dd][ty << 2];
      float4 b4 = *(const float4*)&Bsf[dd][tx << 2];
      float av[4] = {a4.x, a4.y, a4.z, a4.w};
      float bv[4] = {b4.x, b4.y, b4.z, b4.w};
#pragma unroll
      for (int i = 0; i < 4; ++i)
#pragma unroll
        for (int j = 0; j < 4; ++j)
          acc[i][j] = fmaf(av[i], bv[j], acc[i][j]);
    }
    __syncthreads();
  }
  const float inv_nt = 1.f / 8192.f;
  int colC0 = blockIdx.x * 64;
  float eev[4];
#pragma unroll
  for (int j = 0; j < 4; ++j) eev[j] = ee[ks + colC0 + (tx << 2) + j];
#pragma unroll
  for (int i = 0; i < 4; ++i) {
    int grow = row0 + (ty << 2) + i;
    float xxv = xx[grow];
    float4 v;
    v.x = expf((xxv + eev[0] - 2.0f * acc[i][0]) * inv_nt);
    v.y = expf((xxv + eev[1] - 2.0f * acc[i][1]) * inv_nt);
    v.z = expf((xxv + eev[2] - 2.0f * acc[i][2]) * inv_nt);
    v.w = expf((xxv + eev[3] - 2.0f * acc[i][3]) * inv_nt);
    *(float4*)(E + (size_t)grow * KC + colC0 + (tx << 2)) = v;
  }
}

// ---------------- fallback sampler: wave-shared champion + bits screen ----------------
__global__ __launch_bounds__(256) void sample_kernel(const float* __restrict__ E,
                                                     float* __restrict__ rmin,
                                                     int* __restrict__ ridx,
                                                     int ks, int KC,
                                                     uint32_t k0, uint32_t k1) {
  int lane = threadIdx.x & 63;
  int row = (int)((blockIdx.x * blockDim.x + threadIdx.x) >> 6);
  unsigned long long champ[N_SAMP];
  uint32_t th[N_SAMP];
#pragma unroll
  for (int s = 0; s < N_SAMP; ++s) { champ[s] = 0xFFFFFFFFFFFFFFFFULL; th[s] = 0u; }
  const float tiny = 1.1754943508222875e-38f;
  uint32_t row_c = (uint32_t)row * 81920u;
  const float* Erow = E + (size_t)row * KC;

  float Ek = Erow[lane];
  for (int kk = lane; kk < KC; kk += 64) {
    int nk = (kk + 64 < KC) ? kk + 64 : kk;
    float Ekn = Erow[nk];
    uint32_t k = (uint32_t)(ks + kk);
    uint32_t base_c = row_c + k;
#pragma unroll
    for (int s = 0; s < N_SAMP; ++s) {
      uint32_t x0 = 0u, x1 = base_c + (uint32_t)s * 8192u;
      tf2x32(k0, k1, x0, x1);
      uint32_t bits = x0 ^ x1;
      bool cand = (bits >= th[s]);
      if (__any(cand)) {
        float u = __uint_as_float(0x3f800000u | (bits >> 9)) - 1.0f;
        u = fmaxf(u, tiny);
        float wv = -logf(u) * Ek;
        unsigned long long p = cand
            ? (((unsigned long long)__float_as_uint(wv) << 32) | k)
            : 0xFFFFFFFFFFFFFFFFULL;
#pragma unroll
        for (int off = 1; off < 64; off <<= 1) {
          unsigned long long op = shfl_xor_u64(p, off);
          p = (op < p) ? op : p;
        }
        if (p < champ[s]) {
          champ[s] = p;
          float wmin = __uint_as_float((uint32_t)(p >> 32));
          float ut = expf(-wmin) * 0.999999f;
          th[s] = ((uint32_t)(ut * 8388608.0f)) << 9;
        }
      }
    }
    Ek = Ekn;
  }
#pragma unroll
  for (int s = 0; s < N_SAMP; ++s) {
    if (lane == 0) {
      float v = __uint_as_float((uint32_t)(champ[s] >> 32));
      int id = (int)(uint32_t)(champ[s] & 0xFFFFFFFFu);
      size_t p = (size_t)row * N_SAMP + s;
      if (v < rmin[p]) { rmin[p] = v; ridx[p] = id; }
    }
  }
}

// ---------------- gather + mean + straight-through (u64 champion version) ----------------
__global__ __launch_bounds__(256) void gather_kernel(const float* __restrict__ emb,
                                                     const unsigned long long* __restrict__ champ,
                                                     const float* __restrict__ x,
                                                     float* __restrict__ outq,
                                                     float* __restrict__ outs) {
  int lane = threadIdx.x & 63;
  int row = (int)((blockIdx.x * blockDim.x + threadIdx.x) >> 6);
  int idx[N_SAMP];
#pragma unroll
  for (int s = 0; s < N_SAMP; ++s)
    idx[s] = (int)(uint32_t)(champ[(size_t)row * N_SAMP + s] & 0xFFFFFFFFu);
  if (lane < N_SAMP) outs[row * N_SAMP + lane] = (float)idx[lane];
#pragma unroll
  for (int h = 0; h < 2; ++h) {
    int c = h * 256 + lane * 4;
    float4 sum = make_float4(0.f, 0.f, 0.f, 0.f);
#pragma unroll
    for (int s = 0; s < N_SAMP; ++s) {
      float4 e = *(const float4*)(emb + (size_t)idx[s] * N_DIM + c);
      sum.x += e.x; sum.y += e.y; sum.z += e.z; sum.w += e.w;
    }
    float4 xv = *(const float4*)(x + (size_t)row * N_DIM + c);
    float4 o;
    o.x = xv.x + (sum.x / 10.0f - xv.x);
    o.y = xv.y + (sum.y / 10.0f - xv.y);
    o.z = xv.z + (sum.z / 10.0f - xv.z);
    o.w = xv.w + (sum.w / 10.0f - xv.w);
    *(float4*)(outq + (size_t)row * N_DIM + c) = o;
  }
}

// ---------------- fallback gather (int ridx version) ----------------
__global__ __launch_bounds__(256) void gather_fb_kernel(const float* __restrict__ emb,
                                                        const int* __restrict__ ridx,
                                                        const float* __restrict__ x,
                                                        float* __restrict__ outq,
                                                        float* __restrict__ outs) {
  int lane = threadIdx.x & 63;
  int row = (int)((blockIdx.x * blockDim.x + threadIdx.x) >> 6);
  int idx[N_SAMP];
#pragma unroll
  for (int s = 0; s < N_SAMP; ++s) idx[s] = ridx[row * N_SAMP + s];
  if (lane < N_SAMP) outs[row * N_SAMP + lane] = (float)idx[lane];
#pragma unroll
  for (int h = 0; h < 2; ++h) {
    int c = h * 256 + lane * 4;
    float4 sum = make_float4(0.f, 0.f, 0.f, 0.f);
#pragma unroll
    for (int s = 0; s < N_SAMP; ++s) {
      float4 e = *(const float4*)(emb + (size_t)idx[s] * N_DIM + c);
      sum.x += e.x; sum.y += e.y; sum.z += e.z; sum.w += e.w;
    }
    float4 xv = *(const float4*)(x + (size_t)row * N_DIM + c);
    float4 o;
    o.x = xv.x + (sum.x / 10.0f - xv.x);
    o.y = xv.y + (sum.y / 10.0f - xv.y);
    o.z = xv.z + (sum.z / 10.0f - xv.z);
    o.w = xv.w + (sum.w / 10.0f - xv.w);
    *(float4*)(outq + (size_t)row * N_DIM + c) = o;
  }
}

extern "C" void kernel_launch(void* const* d_in, const int* in_sizes, int n_in,
                              void* d_out, int out_size, void* d_ws, size_t ws_size,
                              hipStream_t stream) {
  const float* x = (const float*)d_in[0];
  const float* emb = (const float*)d_in[1];
  float* out_q = (float*)d_out;
  float* out_s = out_q + (size_t)N_ROWS * N_DIM;

  const size_t split_u = (size_t)N_ROWS * GK;  // ushorts per split buffer
  const size_t fixed_f = (size_t)N_ROWS + N_TOK + 2 * (size_t)N_ROWS * N_SAMP;
  const size_t out_f = (size_t)N_ROWS * N_DIM + (size_t)N_ROWS * N_SAMP;

  uint32_t s0 = 0u, s1 = 1u;   // skey = fold_in(key(0), 1)
  tf2x32(0u, 0u, s0, s1);

  // ---- preferred path: fused bf16x2 MFMA GEMM + sampler (no E materialization) ----
  {
    size_t need = (size_t)(N_ROWS + N_TOK) * 4            // xx, ee
                + (size_t)N_ROWS * N_SAMP * 8             // champ u64
                + 2 * split_u * 2;                        // A2, B2
    if (need <= ws_size) {
      float* xx = (float*)d_ws;
      float* ee = xx + N_ROWS;
      unsigned long long* champ = (unsigned long long*)(ee + N_TOK);
      unsigned short* A2 = (unsigned short*)(champ + (size_t)N_ROWS * N_SAMP);
      unsigned short* B2 = A2 + split_u;

      rownorm_kernel<<<2048, 256, 0, stream>>>(x, xx);
      rownorm_kernel<<<2048, 256, 0, stream>>>(emb, ee);
      init_champ_kernel<<<(N_ROWS * N_SAMP + 255) / 256, 256, 0, stream>>>(champ);
      split_kernel<<<N_ROWS * 128 / 256, 256, 0, stream>>>(x, A2, 0);
      split_kernel<<<N_ROWS * 128 / 256, 256, 0, stream>>>(emb, B2, 1);
      fused_gemm_sample_kernel<<<dim3(N_TOK / 128, N_ROWS / 128), 256, 0, stream>>>(
          A2, B2, xx, ee, champ, s0, s1);
      gather_kernel<<<2048, 256, 0, stream>>>(emb, champ, x, out_q, out_s);
      return;
    }
  }

  // ---- fallback: fp32 path with adaptive placement (r6-proven) ----
  float *xx, *ee, *rmin, *E;
  int* ridx;
  int KC = 0;
  for (int c = 8192; c >= 64; c >>= 1) {
    if ((fixed_f + (size_t)N_ROWS * c) * 4 <= ws_size) { KC = c; break; }
  }
  if (KC) {
    xx = (float*)d_ws;
    ee = xx + N_ROWS;
    rmin = ee + N_TOK;
    ridx = (int*)(rmin + (size_t)N_ROWS * N_SAMP);
    E = (float*)(ridx + (size_t)N_ROWS * N_SAMP);
  } else if (fixed_f * 4 <= ws_size) {
    KC = 512;
    xx = (float*)d_ws;
    ee = xx + N_ROWS;
    rmin = ee + N_TOK;
    ridx = (int*)(rmin + (size_t)N_ROWS * N_SAMP);
    E = out_q;
  } else {
    KC = 256;
    E = out_q;
    float* tail = out_q + (out_f - fixed_f);
    xx = tail;
    ee = xx + N_ROWS;
    rmin = ee + N_TOK;
    ridx = (int*)(rmin + (size_t)N_ROWS * N_SAMP);
  }

  rownorm_kernel<<<2048, 256, 0, stream>>>(x, xx);
  rownorm_kernel<<<2048, 256, 0, stream>>>(emb, ee);
  init_state_kernel<<<(N_ROWS * N_SAMP + 255) / 256, 256, 0, stream>>>(rmin, ridx);
  for (int ks = 0; ks < N_TOK; ks += KC) {
    gemm_nt_kernel<<<dim3(KC / 64, N_ROWS / 64), 256, 0, stream>>>(x, emb, xx, ee, E, ks, KC);
    sample_kernel<<<2048, 256, 0, stream>>>(E, rmin, ridx, ks, KC, s0, s1);
  }
  gather_fb_kernel<<<2048, 256, 0, stream>>>(emb, ridx, x, out_q, out_s);
}

// Round 2
// 2082.748 us; speedup vs baseline: 1.9121x; 1.9121x over previous
//
#include <hip/hip_runtime.h>
#include <stdint.h>
#include <math.h>

#define N_ROWS 8192
#define N_TOK  8192
#define N_DIM  512
#define N_SAMP 10
#define GK     1536   // 3 * 512, bf16x2 split zones

typedef __attribute__((ext_vector_type(8))) short bf16x8_t;
typedef __attribute__((ext_vector_type(4))) float f32x4_t;

// ---------------- JAX threefry2x32 (exact; rotl forced to 1-op alignbit) ----------------
__host__ __device__ __forceinline__ void tf2x32(uint32_t ks0, uint32_t ks1,
                                                uint32_t& x0, uint32_t& x1) {
  uint32_t ks2 = ks0 ^ ks1 ^ 0x1BD11BDAu;
  x0 += ks0; x1 += ks1;
#define TF_ROUND(r) { x0 += x1; x1 = __builtin_rotateleft32(x1, r); x1 ^= x0; }
  TF_ROUND(13) TF_ROUND(15) TF_ROUND(26) TF_ROUND(6)
  x0 += ks1; x1 += ks2 + 1u;
  TF_ROUND(17) TF_ROUND(29) TF_ROUND(16) TF_ROUND(24)
  x0 += ks2; x1 += ks0 + 2u;
  TF_ROUND(13) TF_ROUND(15) TF_ROUND(26) TF_ROUND(6)
  x0 += ks0; x1 += ks1 + 3u;
  TF_ROUND(17) TF_ROUND(29) TF_ROUND(16) TF_ROUND(24)
  x0 += ks1; x1 += ks2 + 4u;
  TF_ROUND(13) TF_ROUND(15) TF_ROUND(26) TF_ROUND(6)
  x0 += ks2; x1 += ks0 + 5u;
#undef TF_ROUND
}

__device__ __forceinline__ unsigned short f2bf_rne(float f) {
  uint32_t u = __float_as_uint(f);
  uint32_t r = (u + 0x7fffu + ((u >> 16) & 1u)) >> 16;
  return (unsigned short)r;
}
__device__ __forceinline__ float bf2f(unsigned short h) {
  return __uint_as_float((uint32_t)h << 16);
}

__device__ __forceinline__ unsigned long long shfl_xor_u64(unsigned long long v, int off) {
  uint32_t lo = (uint32_t)v, hi = (uint32_t)(v >> 32);
  lo = (uint32_t)__shfl_xor((int)lo, off, 64);
  hi = (uint32_t)__shfl_xor((int)hi, off, 64);
  return ((unsigned long long)hi << 32) | lo;
}

// ---------------- row sum-of-squares ----------------
__global__ __launch_bounds__(256) void rownorm_kernel(const float* __restrict__ M,
                                                      float* __restrict__ out) {
  int lane = threadIdx.x & 63;
  int row = (int)((blockIdx.x * blockDim.x + threadIdx.x) >> 6);
  const float* p = M + (size_t)row * N_DIM;
  float acc = 0.f;
#pragma unroll
  for (int d = 0; d < N_DIM; d += 64) {
    float v = p[d + lane];
    acc = fmaf(v, v, acc);
  }
#pragma unroll
  for (int off = 32; off; off >>= 1) acc += __shfl_xor(acc, off, 64);
  if (lane == 0) out[row] = acc;
}

// ---------------- state init ----------------
__global__ __launch_bounds__(256) void init_champ_kernel(unsigned long long* __restrict__ c) {
  int i = blockIdx.x * 256 + threadIdx.x;
  if (i < N_ROWS * N_SAMP) c[i] = 0xFFFFFFFFFFFFFFFFULL;
}

__global__ __launch_bounds__(256) void init_state_kernel(float* __restrict__ rmin,
                                                         int* __restrict__ ridx) {
  int i = blockIdx.x * 256 + threadIdx.x;
  if (i < N_ROWS * N_SAMP) { rmin[i] = INFINITY; ridx[i] = 0; }
}

// ---------------- bf16x2 split ----------------
__global__ __launch_bounds__(256) void split_kernel(const float* __restrict__ src,
                                                    unsigned short* __restrict__ dst,
                                                    int mode) {
  int t = blockIdx.x * 256 + threadIdx.x;
  int row = t >> 7;
  int c = (t & 127) << 2;
  float4 v = *(const float4*)(src + (size_t)row * N_DIM + c);
  ushort4 hi, lo;
  hi.x = f2bf_rne(v.x); lo.x = f2bf_rne(v.x - bf2f(hi.x));
  hi.y = f2bf_rne(v.y); lo.y = f2bf_rne(v.y - bf2f(hi.y));
  hi.z = f2bf_rne(v.z); lo.z = f2bf_rne(v.z - bf2f(hi.z));
  hi.w = f2bf_rne(v.w); lo.w = f2bf_rne(v.w - bf2f(hi.w));
  unsigned short* base = dst + (size_t)row * GK;
  *(ushort4*)(base + c) = hi;
  if (mode == 0) {
    *(ushort4*)(base + 512 + c) = lo;
    *(ushort4*)(base + 1024 + c) = hi;
  } else {
    *(ushort4*)(base + 512 + c) = hi;
    *(ushort4*)(base + 1024 + c) = lo;
  }
}

__device__ __forceinline__ void async_cp16(const void* g, void* l) {
  __builtin_amdgcn_global_load_lds((const __attribute__((address_space(1))) void*)g,
                                   (__attribute__((address_space(3))) void*)l, 16, 0, 0);
}

// ---------------- FUSED bf16 MFMA GEMM + serial-style multinomial sampler ----------------
// GEMM identical to the proven gemm_bf16_kernel. Epilogue v2:
//  (1) every thread writes its 64 values as Ek = expf(dist) into a 128x128 f32
//      LDS tile (XOR-swizzled col^(row&31): scan reads are 2-way = free),
//      reusing the As/Bs staging space (64 KB exactly).
//  (2) each thread serially scans 64 cols of ONE row with a thread-private
//      running bits-screen (exact serial-sampler arithmetic), seeded from a
//      snapshot of the global champion (stale/torn only loosens -> conservative;
//      local champion seeded to u64 MAX so the winner is always published).
//  (3) one atomicMin per (thread, sample) only when a local candidate was found.
// No ballots, no shuffle reduces, exp hoisted out of the s-loop.
__global__ __launch_bounds__(256) void fused_gemm_sample_kernel(
    const unsigned short* __restrict__ A2, const unsigned short* __restrict__ B2,
    const float* __restrict__ xx, const float* __restrict__ ee,
    unsigned long long* __restrict__ champ, uint32_t k0, uint32_t k1) {
  __shared__ __align__(16) unsigned char smem[65536];
  unsigned short* As = (unsigned short*)smem;              // 128*64 ushort = 16 KB
  unsigned short* Bs = (unsigned short*)(smem + 16384);    // 16 KB
  float* Et = (float*)smem;                                // 128*128 f32 = 64 KB (reuse)
  int tid = threadIdx.x;
  int w = tid >> 6, l = tid & 63;

  // banded swizzle: 64 consecutive bids cover an 8x8 supertile (~6 MB hot set).
  int gx = gridDim.x;
  int bid = blockIdx.y * gx + blockIdx.x;
  int band = bid / (8 * gx);
  int t8 = bid % (8 * gx);
  int by = band * 8 + (t8 & 7);
  int bx = t8 >> 3;

  int row0 = by * 128;
  int col0 = bx * 128;
  int wm = (w & 1) * 64, wn = (w >> 1) * 64;
  int quad = l >> 4, r15 = l & 15;

  f32x4_t acc[4][4];
#pragma unroll
  for (int i = 0; i < 4; ++i)
#pragma unroll
    for (int j = 0; j < 4; ++j) acc[i][j] = (f32x4_t){0.f, 0.f, 0.f, 0.f};

  int srow[4], skc[4];
#pragma unroll
  for (int r = 0; r < 4; ++r) {
    int c = tid + 256 * r;
    srow[r] = c >> 3;
    skc[r] = (c & 7) ^ (srow[r] & 7);
  }

  for (int kt = 0; kt < GK; kt += 64) {
#pragma unroll
    for (int r = 0; r < 4; ++r) {
      int c = tid + 256 * r;
      async_cp16(A2 + (size_t)(row0 + srow[r]) * GK + kt + skc[r] * 8, As + c * 8);
      async_cp16(B2 + (size_t)(col0 + srow[r]) * GK + kt + skc[r] * 8, Bs + c * 8);
    }
    __syncthreads();

#pragma unroll
    for (int kk2 = 0; kk2 < 2; ++kk2) {
      bf16x8_t af[4], bf[4];
#pragma unroll
      for (int i = 0; i < 4; ++i) {
        int row = wm + i * 16 + r15;
        int qc = (kk2 * 4 + quad) ^ (r15 & 7);
        af[i] = *(const bf16x8_t*)&As[row * 64 + qc * 8];
      }
#pragma unroll
      for (int j = 0; j < 4; ++j) {
        int row = wn + j * 16 + r15;
        int qc = (kk2 * 4 + quad) ^ (r15 & 7);
        bf[j] = *(const bf16x8_t*)&Bs[row * 64 + qc * 8];
      }
#pragma unroll
      for (int i = 0; i < 4; ++i)
#pragma unroll
        for (int j = 0; j < 4; ++j)
          acc[i][j] = __builtin_amdgcn_mfma_f32_16x16x32_bf16(af[i], bf[j], acc[i][j], 0, 0, 0);
    }
    __syncthreads();
  }

  // ---- (1) write Ek tile to LDS (exp hoisted: exactly once per element) ----
  const float inv_nt = 1.f / 8192.f;
  float eev[4];
#pragma unroll
  for (int j = 0; j < 4; ++j) eev[j] = ee[col0 + wn + j * 16 + r15];
#pragma unroll
  for (int i = 0; i < 4; ++i) {
#pragma unroll
    for (int r = 0; r < 4; ++r) {
      int lrow = wm + i * 16 + quad * 4 + r;
      float xxv = xx[row0 + lrow];
      int mxr = lrow & 31;
#pragma unroll
      for (int j = 0; j < 4; ++j) {
        int col = wn + j * 16 + r15;
        float dist = (xxv + eev[j] - 2.0f * acc[i][j][r]) * inv_nt;
        Et[lrow * 128 + (col ^ mxr)] = expf(dist);   // bit-identical to r6 E value
      }
    }
  }
  __syncthreads();

  // ---- (2) serial scan: thread = (row, column-half) ----
  int lrow = tid >> 1, half = tid & 1;
  int grow = row0 + lrow;
  unsigned long long* cg = champ + (size_t)grow * N_SAMP;
  unsigned long long cw[N_SAMP];
  uint32_t th[N_SAMP];
  int improved = 0;
#pragma unroll
  for (int s = 0; s < N_SAMP; ++s) {
    unsigned long long c = cg[s];          // snapshot: stale/torn only -> looser screen
    cw[s] = 0xFFFFFFFFFFFFFFFFULL;         // local champion independent of snapshot
    uint32_t hi = (uint32_t)(c >> 32);
    uint32_t t = 0u;
    if (hi < 0x7F800000u) {
      float ut = expf(-__uint_as_float(hi)) * 0.999999f;  // conservative (Ek>=1)
      t = ((uint32_t)(ut * 8388608.0f)) << 9;
    }
    th[s] = t;
  }
  const float tiny = 1.1754943508222875e-38f;
  uint32_t row_c = (uint32_t)grow * 81920u;
  const float* Erow = Et + lrow * 128 + half * 64;
  int mxr = lrow & 31;
  uint32_t kbase = (uint32_t)(col0 + half * 64);

  for (int kk = 0; kk < 64; ++kk) {
    float Ek = Erow[kk ^ mxr];
    uint32_t base_c = row_c + kbase + (uint32_t)kk;
#pragma unroll
    for (int s = 0; s < N_SAMP; ++s) {
      uint32_t x0 = 0u, x1 = base_c + (uint32_t)s * 8192u;
      tf2x32(k0, k1, x0, x1);
      uint32_t bits = x0 ^ x1;
      if (bits >= th[s]) {
        float u = __uint_as_float(0x3f800000u | (bits >> 9)) - 1.0f;
        u = fmaxf(u, tiny);
        float wv = -logf(u) * Ek;            // exact r6 arithmetic
        unsigned long long p = ((unsigned long long)__float_as_uint(wv) << 32)
                             | (kbase + (uint32_t)kk);
        if (p < cw[s]) {
          cw[s] = p;
          float ut = expf(-wv) * 0.999999f;
          uint32_t nt = ((uint32_t)(ut * 8388608.0f)) << 9;
          th[s] = (nt > th[s]) ? nt : th[s]; // never loosen below snapshot screen
          improved |= (1 << s);
        }
      }
    }
  }
#pragma unroll
  for (int s = 0; s < N_SAMP; ++s)
    if (improved & (1 << s)) atomicMin(&cg[s], cw[s]);
}

// ---------------- fp32 NT GEMM (fallback, r6-proven) with E-epilogue ----------------
__global__ __launch_bounds__(256) void gemm_nt_kernel(const float* __restrict__ A,
                                                      const float* __restrict__ B,
                                                      const float* __restrict__ xx,
                                                      const float* __restrict__ ee,
                                                      float* __restrict__ E,
                                                      int ks, int KC) {
  __shared__ __align__(16) float Asf[32][68];
  __shared__ __align__(16) float Bsf[32][68];
  int tid = threadIdx.x;
  int row0 = blockIdx.y * 64;
  int colB0 = blockIdx.x * 64 + ks;
  int tx = tid & 15, ty = tid >> 4;
  float acc[4][4] = {};
  for (int d0 = 0; d0 < N_DIM; d0 += 32) {
#pragma unroll
    for (int r = 0; r < 2; ++r) {
      int c = tid + 256 * r;
      int m = c >> 3;
      int dv = (c & 7) << 2;
      const float4 va = *(const float4*)(A + (size_t)(row0 + m) * N_DIM + d0 + dv);
      Asf[dv + 0][m] = va.x; Asf[dv + 1][m] = va.y;
      Asf[dv + 2][m] = va.z; Asf[dv + 3][m] = va.w;
      const float4 vb = *(const float4*)(B + (size_t)(colB0 + m) * N_DIM + d0 + dv);
      Bsf[dv + 0][m] = vb.x; Bsf[dv + 1][m] = vb.y;
      Bsf[dv + 2][m] = vb.z; Bsf[dv + 3][m] = vb.w;
    }
    __syncthreads();
#pragma unroll
    for (int dd = 0; dd < 32; ++dd) {
      float4 a4 = *(const float4*)&Asf[dd][ty << 2];
      float4 b4 = *(const float4*)&Bsf[dd][tx << 2];
      float av[4] = {a4.x, a4.y, a4.z, a4.w};
      float bv[4] = {b4.x, b4.y, b4.z, b4.w};
#pragma unroll
      for (int i = 0; i < 4; ++i)
#pragma unroll
        for (int j = 0; j < 4; ++j)
          acc[i][j] = fmaf(av[i], bv[j], acc[i][j]);
    }
    __syncthreads();
  }
  const float inv_nt = 1.f / 8192.f;
  int colC0 = blockIdx.x * 64;
  float eev[4];
#pragma unroll
  for (int j = 0; j < 4; ++j) eev[j] = ee[ks + colC0 + (tx << 2) + j];
#pragma unroll
  for (int i = 0; i < 4; ++i) {
    int grow = row0 + (ty << 2) + i;
    float xxv = xx[grow];
    float4 v;
    v.x = expf((xxv + eev[0] - 2.0f * acc[i][0]) * inv_nt);
    v.y = expf((xxv + eev[1] - 2.0f * acc[i][1]) * inv_nt);
    v.z = expf((xxv + eev[2] - 2.0f * acc[i][2]) * inv_nt);
    v.w = expf((xxv + eev[3] - 2.0f * acc[i][3]) * inv_nt);
    *(float4*)(E + (size_t)grow * KC + colC0 + (tx << 2)) = v;
  }
}

// ---------------- fallback sampler: wave-shared champion + bits screen ----------------
__global__ __launch_bounds__(256) void sample_kernel(const float* __restrict__ E,
                                                     float* __restrict__ rmin,
                                                     int* __restrict__ ridx,
                                                     int ks, int KC,
                                                     uint32_t k0, uint32_t k1) {
  int lane = threadIdx.x & 63;
  int row = (int)((blockIdx.x * blockDim.x + threadIdx.x) >> 6);
  unsigned long long champ[N_SAMP];
  uint32_t th[N_SAMP];
#pragma unroll
  for (int s = 0; s < N_SAMP; ++s) { champ[s] = 0xFFFFFFFFFFFFFFFFULL; th[s] = 0u; }
  const float tiny = 1.1754943508222875e-38f;
  uint32_t row_c = (uint32_t)row * 81920u;
  const float* Erow = E + (size_t)row * KC;

  float Ek = Erow[lane];
  for (int kk = lane; kk < KC; kk += 64) {
    int nk = (kk + 64 < KC) ? kk + 64 : kk;
    float Ekn = Erow[nk];
    uint32_t k = (uint32_t)(ks + kk);
    uint32_t base_c = row_c + k;
#pragma unroll
    for (int s = 0; s < N_SAMP; ++s) {
      uint32_t x0 = 0u, x1 = base_c + (uint32_t)s * 8192u;
      tf2x32(k0, k1, x0, x1);
      uint32_t bits = x0 ^ x1;
      bool cand = (bits >= th[s]);
      if (__any(cand)) {
        float u = __uint_as_float(0x3f800000u | (bits >> 9)) - 1.0f;
        u = fmaxf(u, tiny);
        float wv = -logf(u) * Ek;
        unsigned long long p = cand
            ? (((unsigned long long)__float_as_uint(wv) << 32) | k)
            : 0xFFFFFFFFFFFFFFFFULL;
#pragma unroll
        for (int off = 1; off < 64; off <<= 1) {
          unsigned long long op = shfl_xor_u64(p, off);
          p = (op < p) ? op : p;
        }
        if (p < champ[s]) {
          champ[s] = p;
          float wmin = __uint_as_float((uint32_t)(p >> 32));
          float ut = expf(-wmin) * 0.999999f;
          th[s] = ((uint32_t)(ut * 8388608.0f)) << 9;
        }
      }
    }
    Ek = Ekn;
  }
#pragma unroll
  for (int s = 0; s < N_SAMP; ++s) {
    if (lane == 0) {
      float v = __uint_as_float((uint32_t)(champ[s] >> 32));
      int id = (int)(uint32_t)(champ[s] & 0xFFFFFFFFu);
      size_t p = (size_t)row * N_SAMP + s;
      if (v < rmin[p]) { rmin[p] = v; ridx[p] = id; }
    }
  }
}

// ---------------- gather + mean + straight-through (u64 champion version) ----------------
__global__ __launch_bounds__(256) void gather_kernel(const float* __restrict__ emb,
                                                     const unsigned long long* __restrict__ champ,
                                                     const float* __restrict__ x,
                                                     float* __restrict__ outq,
                                                     float* __restrict__ outs) {
  int lane = threadIdx.x & 63;
  int row = (int)((blockIdx.x * blockDim.x + threadIdx.x) >> 6);
  int idx[N_SAMP];
#pragma unroll
  for (int s = 0; s < N_SAMP; ++s)
    idx[s] = (int)(uint32_t)(champ[(size_t)row * N_SAMP + s] & 0xFFFFFFFFu);
  if (lane < N_SAMP) outs[row * N_SAMP + lane] = (float)idx[lane];
#pragma unroll
  for (int h = 0; h < 2; ++h) {
    int c = h * 256 + lane * 4;
    float4 sum = make_float4(0.f, 0.f, 0.f, 0.f);
#pragma unroll
    for (int s = 0; s < N_SAMP; ++s) {
      float4 e = *(const float4*)(emb + (size_t)idx[s] * N_DIM + c);
      sum.x += e.x; sum.y += e.y; sum.z += e.z; sum.w += e.w;
    }
    float4 xv = *(const float4*)(x + (size_t)row * N_DIM + c);
    float4 o;
    o.x = xv.x + (sum.x / 10.0f - xv.x);
    o.y = xv.y + (sum.y / 10.0f - xv.y);
    o.z = xv.z + (sum.z / 10.0f - xv.z);
    o.w = xv.w + (sum.w / 10.0f - xv.w);
    *(float4*)(outq + (size_t)row * N_DIM + c) = o;
  }
}

// ---------------- fallback gather (int ridx version) ----------------
__global__ __launch_bounds__(256) void gather_fb_kernel(const float* __restrict__ emb,
                                                        const int* __restrict__ ridx,
                                                        const float* __restrict__ x,
                                                        float* __restrict__ outq,
                                                        float* __restrict__ outs) {
  int lane = threadIdx.x & 63;
  int row = (int)((blockIdx.x * blockDim.x + threadIdx.x) >> 6);
  int idx[N_SAMP];
#pragma unroll
  for (int s = 0; s < N_SAMP; ++s) idx[s] = ridx[row * N_SAMP + s];
  if (lane < N_SAMP) outs[row * N_SAMP + lane] = (float)idx[lane];
#pragma unroll
  for (int h = 0; h < 2; ++h) {
    int c = h * 256 + lane * 4;
    float4 sum = make_float4(0.f, 0.f, 0.f, 0.f);
#pragma unroll
    for (int s = 0; s < N_SAMP; ++s) {
      float4 e = *(const float4*)(emb + (size_t)idx[s] * N_DIM + c);
      sum.x += e.x; sum.y += e.y; sum.z += e.z; sum.w += e.w;
    }
    float4 xv = *(const float4*)(x + (size_t)row * N_DIM + c);
    float4 o;
    o.x = xv.x + (sum.x / 10.0f - xv.x);
    o.y = xv.y + (sum.y / 10.0f - xv.y);
    o.z = xv.z + (sum.z / 10.0f - xv.z);
    o.w = xv.w + (sum.w / 10.0f - xv.w);
    *(float4*)(outq + (size_t)row * N_DIM + c) = o;
  }
}

extern "C" void kernel_launch(void* const* d_in, const int* in_sizes, int n_in,
                              void* d_out, int out_size, void* d_ws, size_t ws_size,
                              hipStream_t stream) {
  const float* x = (const float*)d_in[0];
  const float* emb = (const float*)d_in[1];
  float* out_q = (float*)d_out;
  float* out_s = out_q + (size_t)N_ROWS * N_DIM;

  const size_t split_u = (size_t)N_ROWS * GK;  // ushorts per split buffer
  const size_t fixed_f = (size_t)N_ROWS + N_TOK + 2 * (size_t)N_ROWS * N_SAMP;
  const size_t out_f = (size_t)N_ROWS * N_DIM + (size_t)N_ROWS * N_SAMP;

  uint32_t s0 = 0u, s1 = 1u;   // skey = fold_in(key(0), 1)
  tf2x32(0u, 0u, s0, s1);

  // ---- preferred path: fused bf16x2 MFMA GEMM + sampler (no E materialization) ----
  {
    size_t need = (size_t)(N_ROWS + N_TOK) * 4            // xx, ee
                + (size_t)N_ROWS * N_SAMP * 8             // champ u64
                + 2 * split_u * 2;                        // A2, B2
    if (need <= ws_size) {
      float* xx = (float*)d_ws;
      float* ee = xx + N_ROWS;
      unsigned long long* champ = (unsigned long long*)(ee + N_TOK);
      unsigned short* A2 = (unsigned short*)(champ + (size_t)N_ROWS * N_SAMP);
      unsigned short* B2 = A2 + split_u;

      rownorm_kernel<<<2048, 256, 0, stream>>>(x, xx);
      rownorm_kernel<<<2048, 256, 0, stream>>>(emb, ee);
      init_champ_kernel<<<(N_ROWS * N_SAMP + 255) / 256, 256, 0, stream>>>(champ);
      split_kernel<<<N_ROWS * 128 / 256, 256, 0, stream>>>(x, A2, 0);
      split_kernel<<<N_ROWS * 128 / 256, 256, 0, stream>>>(emb, B2, 1);
      fused_gemm_sample_kernel<<<dim3(N_TOK / 128, N_ROWS / 128), 256, 0, stream>>>(
          A2, B2, xx, ee, champ, s0, s1);
      gather_kernel<<<2048, 256, 0, stream>>>(emb, champ, x, out_q, out_s);
      return;
    }
  }

  // ---- fallback: fp32 path with adaptive placement (r6-proven) ----
  float *xx, *ee, *rmin, *E;
  int* ridx;
  int KC = 0;
  for (int c = 8192; c >= 64; c >>= 1) {
    if ((fixed_f + (size_t)N_ROWS * c) * 4 <= ws_size) { KC = c; break; }
  }
  if (KC) {
    xx = (float*)d_ws;
    ee = xx + N_ROWS;
    rmin = ee + N_TOK;
    ridx = (int*)(rmin + (size_t)N_ROWS * N_SAMP);
    E = (float*)(ridx + (size_t)N_ROWS * N_SAMP);
  } else if (fixed_f * 4 <= ws_size) {
    KC = 512;
    xx = (float*)d_ws;
    ee = xx + N_ROWS;
    rmin = ee + N_TOK;
    ridx = (int*)(rmin + (size_t)N_ROWS * N_SAMP);
    E = out_q;
  } else {
    KC = 256;
    E = out_q;
    float* tail = out_q + (out_f - fixed_f);
    xx = tail;
    ee = xx + N_ROWS;
    rmin = ee + N_TOK;
    ridx = (int*)(rmin + (size_t)N_ROWS * N_SAMP);
  }

  rownorm_kernel<<<2048, 256, 0, stream>>>(x, xx);
  rownorm_kernel<<<2048, 256, 0, stream>>>(emb, ee);
  init_state_kernel<<<(N_ROWS * N_SAMP + 255) / 256, 256, 0, stream>>>(rmin, ridx);
  for (int ks = 0; ks < N_TOK; ks += KC) {
    gemm_nt_kernel<<<dim3(KC / 64, N_ROWS / 64), 256, 0, stream>>>(x, emb, xx, ee, E, ks, KC);
    sample_kernel<<<2048, 256, 0, stream>>>(E, rmin, ridx, ks, KC, s0, s1);
  }
  gather_fb_kernel<<<2048, 256, 0, stream>>>(emb, ridx, x, out_q, out_s);
}

// Round 3
// 1528.080 us; speedup vs baseline: 2.6061x; 1.3630x over previous
//
#include <hip/hip_runtime.h>
#include <stdint.h>
#include <math.h>

#define N_ROWS 8192
#define N_TOK  8192
#define N_DIM  512
#define N_SAMP 10
#define GK     1536   // 3 * 512, bf16x2 split zones

typedef __attribute__((ext_vector_type(8))) short bf16x8_t;
typedef __attribute__((ext_vector_type(4))) float f32x4_t;

// ---------------- JAX threefry2x32 (exact; rotl forced to 1-op alignbit) ----------------
__host__ __device__ __forceinline__ void tf2x32(uint32_t ks0, uint32_t ks1,
                                                uint32_t& x0, uint32_t& x1) {
  uint32_t ks2 = ks0 ^ ks1 ^ 0x1BD11BDAu;
  x0 += ks0; x1 += ks1;
#define TF_ROUND(r) { x0 += x1; x1 = __builtin_rotateleft32(x1, r); x1 ^= x0; }
  TF_ROUND(13) TF_ROUND(15) TF_ROUND(26) TF_ROUND(6)
  x0 += ks1; x1 += ks2 + 1u;
  TF_ROUND(17) TF_ROUND(29) TF_ROUND(16) TF_ROUND(24)
  x0 += ks2; x1 += ks0 + 2u;
  TF_ROUND(13) TF_ROUND(15) TF_ROUND(26) TF_ROUND(6)
  x0 += ks0; x1 += ks1 + 3u;
  TF_ROUND(17) TF_ROUND(29) TF_ROUND(16) TF_ROUND(24)
  x0 += ks1; x1 += ks2 + 4u;
  TF_ROUND(13) TF_ROUND(15) TF_ROUND(26) TF_ROUND(6)
  x0 += ks2; x1 += ks0 + 5u;
#undef TF_ROUND
}

__device__ __forceinline__ unsigned short f2bf_rne(float f) {
  uint32_t u = __float_as_uint(f);
  uint32_t r = (u + 0x7fffu + ((u >> 16) & 1u)) >> 16;
  return (unsigned short)r;
}
__device__ __forceinline__ float bf2f(unsigned short h) {
  return __uint_as_float((uint32_t)h << 16);
}

__device__ __forceinline__ unsigned long long shfl_xor_u64(unsigned long long v, int off) {
  uint32_t lo = (uint32_t)v, hi = (uint32_t)(v >> 32);
  lo = (uint32_t)__shfl_xor((int)lo, off, 64);
  hi = (uint32_t)__shfl_xor((int)hi, off, 64);
  return ((unsigned long long)hi << 32) | lo;
}

// ---------------- row sum-of-squares ----------------
__global__ __launch_bounds__(256) void rownorm_kernel(const float* __restrict__ M,
                                                      float* __restrict__ out) {
  int lane = threadIdx.x & 63;
  int row = (int)((blockIdx.x * blockDim.x + threadIdx.x) >> 6);
  const float* p = M + (size_t)row * N_DIM;
  float acc = 0.f;
#pragma unroll
  for (int d = 0; d < N_DIM; d += 64) {
    float v = p[d + lane];
    acc = fmaf(v, v, acc);
  }
#pragma unroll
  for (int off = 32; off; off >>= 1) acc += __shfl_xor(acc, off, 64);
  if (lane == 0) out[row] = acc;
}

// ---------------- state init ----------------
__global__ __launch_bounds__(256) void init_champ_kernel(unsigned long long* __restrict__ c) {
  int i = blockIdx.x * 256 + threadIdx.x;
  if (i < N_ROWS * N_SAMP) c[i] = 0xFFFFFFFFFFFFFFFFULL;
}

__global__ __launch_bounds__(256) void init_state_kernel(float* __restrict__ rmin,
                                                         int* __restrict__ ridx) {
  int i = blockIdx.x * 256 + threadIdx.x;
  if (i < N_ROWS * N_SAMP) { rmin[i] = INFINITY; ridx[i] = 0; }
}

// ---------------- bf16x2 split ----------------
__global__ __launch_bounds__(256) void split_kernel(const float* __restrict__ src,
                                                    unsigned short* __restrict__ dst,
                                                    int mode) {
  int t = blockIdx.x * 256 + threadIdx.x;
  int row = t >> 7;
  int c = (t & 127) << 2;
  float4 v = *(const float4*)(src + (size_t)row * N_DIM + c);
  ushort4 hi, lo;
  hi.x = f2bf_rne(v.x); lo.x = f2bf_rne(v.x - bf2f(hi.x));
  hi.y = f2bf_rne(v.y); lo.y = f2bf_rne(v.y - bf2f(hi.y));
  hi.z = f2bf_rne(v.z); lo.z = f2bf_rne(v.z - bf2f(hi.z));
  hi.w = f2bf_rne(v.w); lo.w = f2bf_rne(v.w - bf2f(hi.w));
  unsigned short* base = dst + (size_t)row * GK;
  *(ushort4*)(base + c) = hi;
  if (mode == 0) {
    *(ushort4*)(base + 512 + c) = lo;
    *(ushort4*)(base + 1024 + c) = hi;
  } else {
    *(ushort4*)(base + 512 + c) = hi;
    *(ushort4*)(base + 1024 + c) = lo;
  }
}

__device__ __forceinline__ void async_cp16(const void* g, void* l) {
  __builtin_amdgcn_global_load_lds((const __attribute__((address_space(1))) void*)g,
                                   (__attribute__((address_space(3))) void*)l, 16, 0, 0);
}

// ---------------- FUSED bf16 MFMA GEMM + serial-style multinomial sampler ----------------
// v3: block mapping by=bid&63 (fast), bx=bid>>6 (slow) => column-panels run as
// sequential GENERATIONS per row. Later generations snapshot champions published
// by earlier ones -> the bits-screen is tight (accept ~1e-3) and the logf/expf
// accept body almost never executes (v2's banded swizzle made all 64 col-blocks
// of a row concurrent -> empty screens -> accept body on ~all 655M evals).
// Also: for fixed by, all col-blocks have bid==by (mod 8) -> same XCD under
// round-robin dispatch -> champion atomics + snapshot loads share one L2, and
// each XCD's 8 A-panels (3 MB) stay L2-resident across generations.
__global__ __launch_bounds__(256) void fused_gemm_sample_kernel(
    const unsigned short* __restrict__ A2, const unsigned short* __restrict__ B2,
    const float* __restrict__ xx, const float* __restrict__ ee,
    unsigned long long* __restrict__ champ, uint32_t k0, uint32_t k1) {
  __shared__ __align__(16) unsigned char smem[65536];
  unsigned short* As = (unsigned short*)smem;              // 128*64 ushort = 16 KB
  unsigned short* Bs = (unsigned short*)(smem + 16384);    // 16 KB
  float* Et = (float*)smem;                                // 128*128 f32 = 64 KB (reuse)
  int tid = threadIdx.x;
  int w = tid >> 6, l = tid & 63;

  int bid = blockIdx.y * gridDim.x + blockIdx.x;
  int by = bid & 63;   // row-block: fast -> spreads rows across XCDs
  int bx = bid >> 6;   // col-block: slow -> generations, screens tighten

  int row0 = by * 128;
  int col0 = bx * 128;
  int wm = (w & 1) * 64, wn = (w >> 1) * 64;
  int quad = l >> 4, r15 = l & 15;

  f32x4_t acc[4][4];
#pragma unroll
  for (int i = 0; i < 4; ++i)
#pragma unroll
    for (int j = 0; j < 4; ++j) acc[i][j] = (f32x4_t){0.f, 0.f, 0.f, 0.f};

  int srow[4], skc[4];
#pragma unroll
  for (int r = 0; r < 4; ++r) {
    int c = tid + 256 * r;
    srow[r] = c >> 3;
    skc[r] = (c & 7) ^ (srow[r] & 7);
  }

  for (int kt = 0; kt < GK; kt += 64) {
#pragma unroll
    for (int r = 0; r < 4; ++r) {
      int c = tid + 256 * r;
      async_cp16(A2 + (size_t)(row0 + srow[r]) * GK + kt + skc[r] * 8, As + c * 8);
      async_cp16(B2 + (size_t)(col0 + srow[r]) * GK + kt + skc[r] * 8, Bs + c * 8);
    }
    __syncthreads();

#pragma unroll
    for (int kk2 = 0; kk2 < 2; ++kk2) {
      bf16x8_t af[4], bf[4];
#pragma unroll
      for (int i = 0; i < 4; ++i) {
        int row = wm + i * 16 + r15;
        int qc = (kk2 * 4 + quad) ^ (r15 & 7);
        af[i] = *(const bf16x8_t*)&As[row * 64 + qc * 8];
      }
#pragma unroll
      for (int j = 0; j < 4; ++j) {
        int row = wn + j * 16 + r15;
        int qc = (kk2 * 4 + quad) ^ (r15 & 7);
        bf[j] = *(const bf16x8_t*)&Bs[row * 64 + qc * 8];
      }
#pragma unroll
      for (int i = 0; i < 4; ++i)
#pragma unroll
        for (int j = 0; j < 4; ++j)
          acc[i][j] = __builtin_amdgcn_mfma_f32_16x16x32_bf16(af[i], bf[j], acc[i][j], 0, 0, 0);
    }
    __syncthreads();
  }

  // ---- (1) write Ek tile to LDS (exp hoisted: exactly once per element) ----
  const float inv_nt = 1.f / 8192.f;
  float eev[4];
#pragma unroll
  for (int j = 0; j < 4; ++j) eev[j] = ee[col0 + wn + j * 16 + r15];
#pragma unroll
  for (int i = 0; i < 4; ++i) {
#pragma unroll
    for (int r = 0; r < 4; ++r) {
      int lrow = wm + i * 16 + quad * 4 + r;
      float xxv = xx[row0 + lrow];
      int mxr = lrow & 31;
#pragma unroll
      for (int j = 0; j < 4; ++j) {
        int col = wn + j * 16 + r15;
        float dist = (xxv + eev[j] - 2.0f * acc[i][j][r]) * inv_nt;
        Et[lrow * 128 + (col ^ mxr)] = expf(dist);   // bit-identical to r6 E value
      }
    }
  }
  __syncthreads();

  // ---- (2) serial scan: thread = (row, column-half) ----
  int lrow = tid >> 1, half = tid & 1;
  int grow = row0 + lrow;
  unsigned long long* cg = champ + (size_t)grow * N_SAMP;
  unsigned long long cw[N_SAMP];
  uint32_t th[N_SAMP];
  int improved = 0;
#pragma unroll
  for (int s = 0; s < N_SAMP; ++s) {
    unsigned long long c = cg[s];          // snapshot: stale/torn only -> looser screen
    cw[s] = 0xFFFFFFFFFFFFFFFFULL;         // local champion independent of snapshot
    uint32_t hi = (uint32_t)(c >> 32);
    uint32_t t = 0u;
    if (hi < 0x7F800000u) {
      float ut = expf(-__uint_as_float(hi)) * 0.999999f;  // conservative (Ek>=1)
      t = ((uint32_t)(ut * 8388608.0f)) << 9;
    }
    th[s] = t;
  }
  const float tiny = 1.1754943508222875e-38f;
  uint32_t row_c = (uint32_t)grow * 81920u;
  const float* Erow = Et + lrow * 128 + half * 64;
  int mxr = lrow & 31;
  uint32_t kbase = (uint32_t)(col0 + half * 64);

  for (int kk = 0; kk < 64; ++kk) {
    float Ek = Erow[kk ^ mxr];
    uint32_t base_c = row_c + kbase + (uint32_t)kk;
#pragma unroll
    for (int s = 0; s < N_SAMP; ++s) {
      uint32_t x0 = 0u, x1 = base_c + (uint32_t)s * 8192u;
      tf2x32(k0, k1, x0, x1);
      uint32_t bits = x0 ^ x1;
      if (bits >= th[s]) {
        float u = __uint_as_float(0x3f800000u | (bits >> 9)) - 1.0f;
        u = fmaxf(u, tiny);
        float wv = -logf(u) * Ek;            // exact r6 arithmetic
        unsigned long long p = ((unsigned long long)__float_as_uint(wv) << 32)
                             | (kbase + (uint32_t)kk);
        if (p < cw[s]) {
          cw[s] = p;
          float ut = expf(-wv) * 0.999999f;
          uint32_t nt = ((uint32_t)(ut * 8388608.0f)) << 9;
          th[s] = (nt > th[s]) ? nt : th[s]; // never loosen below snapshot screen
          improved |= (1 << s);
        }
      }
    }
  }
#pragma unroll
  for (int s = 0; s < N_SAMP; ++s)
    if (improved & (1 << s)) atomicMin(&cg[s], cw[s]);
}

// ---------------- fp32 NT GEMM (fallback, r6-proven) with E-epilogue ----------------
__global__ __launch_bounds__(256) void gemm_nt_kernel(const float* __restrict__ A,
                                                      const float* __restrict__ B,
                                                      const float* __restrict__ xx,
                                                      const float* __restrict__ ee,
                                                      float* __restrict__ E,
                                                      int ks, int KC) {
  __shared__ __align__(16) float Asf[32][68];
  __shared__ __align__(16) float Bsf[32][68];
  int tid = threadIdx.x;
  int row0 = blockIdx.y * 64;
  int colB0 = blockIdx.x * 64 + ks;
  int tx = tid & 15, ty = tid >> 4;
  float acc[4][4] = {};
  for (int d0 = 0; d0 < N_DIM; d0 += 32) {
#pragma unroll
    for (int r = 0; r < 2; ++r) {
      int c = tid + 256 * r;
      int m = c >> 3;
      int dv = (c & 7) << 2;
      const float4 va = *(const float4*)(A + (size_t)(row0 + m) * N_DIM + d0 + dv);
      Asf[dv + 0][m] = va.x; Asf[dv + 1][m] = va.y;
      Asf[dv + 2][m] = va.z; Asf[dv + 3][m] = va.w;
      const float4 vb = *(const float4*)(B + (size_t)(colB0 + m) * N_DIM + d0 + dv);
      Bsf[dv + 0][m] = vb.x; Bsf[dv + 1][m] = vb.y;
      Bsf[dv + 2][m] = vb.z; Bsf[dv + 3][m] = vb.w;
    }
    __syncthreads();
#pragma unroll
    for (int dd = 0; dd < 32; ++dd) {
      float4 a4 = *(const float4*)&Asf[dd][ty << 2];
      float4 b4 = *(const float4*)&Bsf[dd][tx << 2];
      float av[4] = {a4.x, a4.y, a4.z, a4.w};
      float bv[4] = {b4.x, b4.y, b4.z, b4.w};
#pragma unroll
      for (int i = 0; i < 4; ++i)
#pragma unroll
        for (int j = 0; j < 4; ++j)
          acc[i][j] = fmaf(av[i], bv[j], acc[i][j]);
    }
    __syncthreads();
  }
  const float inv_nt = 1.f / 8192.f;
  int colC0 = blockIdx.x * 64;
  float eev[4];
#pragma unroll
  for (int j = 0; j < 4; ++j) eev[j] = ee[ks + colC0 + (tx << 2) + j];
#pragma unroll
  for (int i = 0; i < 4; ++i) {
    int grow = row0 + (ty << 2) + i;
    float xxv = xx[grow];
    float4 v;
    v.x = expf((xxv + eev[0] - 2.0f * acc[i][0]) * inv_nt);
    v.y = expf((xxv + eev[1] - 2.0f * acc[i][1]) * inv_nt);
    v.z = expf((xxv + eev[2] - 2.0f * acc[i][2]) * inv_nt);
    v.w = expf((xxv + eev[3] - 2.0f * acc[i][3]) * inv_nt);
    *(float4*)(E + (size_t)grow * KC + colC0 + (tx << 2)) = v;
  }
}

// ---------------- fallback sampler: wave-shared champion + bits screen ----------------
__global__ __launch_bounds__(256) void sample_kernel(const float* __restrict__ E,
                                                     float* __restrict__ rmin,
                                                     int* __restrict__ ridx,
                                                     int ks, int KC,
                                                     uint32_t k0, uint32_t k1) {
  int lane = threadIdx.x & 63;
  int row = (int)((blockIdx.x * blockDim.x + threadIdx.x) >> 6);
  unsigned long long champ[N_SAMP];
  uint32_t th[N_SAMP];
#pragma unroll
  for (int s = 0; s < N_SAMP; ++s) { champ[s] = 0xFFFFFFFFFFFFFFFFULL; th[s] = 0u; }
  const float tiny = 1.1754943508222875e-38f;
  uint32_t row_c = (uint32_t)row * 81920u;
  const float* Erow = E + (size_t)row * KC;

  float Ek = Erow[lane];
  for (int kk = lane; kk < KC; kk += 64) {
    int nk = (kk + 64 < KC) ? kk + 64 : kk;
    float Ekn = Erow[nk];
    uint32_t k = (uint32_t)(ks + kk);
    uint32_t base_c = row_c + k;
#pragma unroll
    for (int s = 0; s < N_SAMP; ++s) {
      uint32_t x0 = 0u, x1 = base_c + (uint32_t)s * 8192u;
      tf2x32(k0, k1, x0, x1);
      uint32_t bits = x0 ^ x1;
      bool cand = (bits >= th[s]);
      if (__any(cand)) {
        float u = __uint_as_float(0x3f800000u | (bits >> 9)) - 1.0f;
        u = fmaxf(u, tiny);
        float wv = -logf(u) * Ek;
        unsigned long long p = cand
            ? (((unsigned long long)__float_as_uint(wv) << 32) | k)
            : 0xFFFFFFFFFFFFFFFFULL;
#pragma unroll
        for (int off = 1; off < 64; off <<= 1) {
          unsigned long long op = shfl_xor_u64(p, off);
          p = (op < p) ? op : p;
        }
        if (p < champ[s]) {
          champ[s] = p;
          float wmin = __uint_as_float((uint32_t)(p >> 32));
          float ut = expf(-wmin) * 0.999999f;
          th[s] = ((uint32_t)(ut * 8388608.0f)) << 9;
        }
      }
    }
    Ek = Ekn;
  }
#pragma unroll
  for (int s = 0; s < N_SAMP; ++s) {
    if (lane == 0) {
      float v = __uint_as_float((uint32_t)(champ[s] >> 32));
      int id = (int)(uint32_t)(champ[s] & 0xFFFFFFFFu);
      size_t p = (size_t)row * N_SAMP + s;
      if (v < rmin[p]) { rmin[p] = v; ridx[p] = id; }
    }
  }
}

// ---------------- gather + mean + straight-through (u64 champion version) ----------------
__global__ __launch_bounds__(256) void gather_kernel(const float* __restrict__ emb,
                                                     const unsigned long long* __restrict__ champ,
                                                     const float* __restrict__ x,
                                                     float* __restrict__ outq,
                                                     float* __restrict__ outs) {
  int lane = threadIdx.x & 63;
  int row = (int)((blockIdx.x * blockDim.x + threadIdx.x) >> 6);
  int idx[N_SAMP];
#pragma unroll
  for (int s = 0; s < N_SAMP; ++s)
    idx[s] = (int)(uint32_t)(champ[(size_t)row * N_SAMP + s] & 0xFFFFFFFFu);
  if (lane < N_SAMP) outs[row * N_SAMP + lane] = (float)idx[lane];
#pragma unroll
  for (int h = 0; h < 2; ++h) {
    int c = h * 256 + lane * 4;
    float4 sum = make_float4(0.f, 0.f, 0.f, 0.f);
#pragma unroll
    for (int s = 0; s < N_SAMP; ++s) {
      float4 e = *(const float4*)(emb + (size_t)idx[s] * N_DIM + c);
      sum.x += e.x; sum.y += e.y; sum.z += e.z; sum.w += e.w;
    }
    float4 xv = *(const float4*)(x + (size_t)row * N_DIM + c);
    float4 o;
    o.x = xv.x + (sum.x / 10.0f - xv.x);
    o.y = xv.y + (sum.y / 10.0f - xv.y);
    o.z = xv.z + (sum.z / 10.0f - xv.z);
    o.w = xv.w + (sum.w / 10.0f - xv.w);
    *(float4*)(outq + (size_t)row * N_DIM + c) = o;
  }
}

// ---------------- fallback gather (int ridx version) ----------------
__global__ __launch_bounds__(256) void gather_fb_kernel(const float* __restrict__ emb,
                                                        const int* __restrict__ ridx,
                                                        const float* __restrict__ x,
                                                        float* __restrict__ outq,
                                                        float* __restrict__ outs) {
  int lane = threadIdx.x & 63;
  int row = (int)((blockIdx.x * blockDim.x + threadIdx.x) >> 6);
  int idx[N_SAMP];
#pragma unroll
  for (int s = 0; s < N_SAMP; ++s) idx[s] = ridx[row * N_SAMP + s];
  if (lane < N_SAMP) outs[row * N_SAMP + lane] = (float)idx[lane];
#pragma unroll
  for (int h = 0; h < 2; ++h) {
    int c = h * 256 + lane * 4;
    float4 sum = make_float4(0.f, 0.f, 0.f, 0.f);
#pragma unroll
    for (int s = 0; s < N_SAMP; ++s) {
      float4 e = *(const float4*)(emb + (size_t)idx[s] * N_DIM + c);
      sum.x += e.x; sum.y += e.y; sum.z += e.z; sum.w += e.w;
    }
    float4 xv = *(const float4*)(x + (size_t)row * N_DIM + c);
    float4 o;
    o.x = xv.x + (sum.x / 10.0f - xv.x);
    o.y = xv.y + (sum.y / 10.0f - xv.y);
    o.z = xv.z + (sum.z / 10.0f - xv.z);
    o.w = xv.w + (sum.w / 10.0f - xv.w);
    *(float4*)(outq + (size_t)row * N_DIM + c) = o;
  }
}

extern "C" void kernel_launch(void* const* d_in, const int* in_sizes, int n_in,
                              void* d_out, int out_size, void* d_ws, size_t ws_size,
                              hipStream_t stream) {
  const float* x = (const float*)d_in[0];
  const float* emb = (const float*)d_in[1];
  float* out_q = (float*)d_out;
  float* out_s = out_q + (size_t)N_ROWS * N_DIM;

  const size_t split_u = (size_t)N_ROWS * GK;  // ushorts per split buffer
  const size_t fixed_f = (size_t)N_ROWS + N_TOK + 2 * (size_t)N_ROWS * N_SAMP;
  const size_t out_f = (size_t)N_ROWS * N_DIM + (size_t)N_ROWS * N_SAMP;

  uint32_t s0 = 0u, s1 = 1u;   // skey = fold_in(key(0), 1)
  tf2x32(0u, 0u, s0, s1);

  // ---- preferred path: fused bf16x2 MFMA GEMM + sampler (no E materialization) ----
  {
    size_t need = (size_t)(N_ROWS + N_TOK) * 4            // xx, ee
                + (size_t)N_ROWS * N_SAMP * 8             // champ u64
                + 2 * split_u * 2;                        // A2, B2
    if (need <= ws_size) {
      float* xx = (float*)d_ws;
      float* ee = xx + N_ROWS;
      unsigned long long* champ = (unsigned long long*)(ee + N_TOK);
      unsigned short* A2 = (unsigned short*)(champ + (size_t)N_ROWS * N_SAMP);
      unsigned short* B2 = A2 + split_u;

      rownorm_kernel<<<2048, 256, 0, stream>>>(x, xx);
      rownorm_kernel<<<2048, 256, 0, stream>>>(emb, ee);
      init_champ_kernel<<<(N_ROWS * N_SAMP + 255) / 256, 256, 0, stream>>>(champ);
      split_kernel<<<N_ROWS * 128 / 256, 256, 0, stream>>>(x, A2, 0);
      split_kernel<<<N_ROWS * 128 / 256, 256, 0, stream>>>(emb, B2, 1);
      fused_gemm_sample_kernel<<<dim3(64, 64), 256, 0, stream>>>(
          A2, B2, xx, ee, champ, s0, s1);
      gather_kernel<<<2048, 256, 0, stream>>>(emb, champ, x, out_q, out_s);
      return;
    }
  }

  // ---- fallback: fp32 path with adaptive placement (r6-proven) ----
  float *xx, *ee, *rmin, *E;
  int* ridx;
  int KC = 0;
  for (int c = 8192; c >= 64; c >>= 1) {
    if ((fixed_f + (size_t)N_ROWS * c) * 4 <= ws_size) { KC = c; break; }
  }
  if (KC) {
    xx = (float*)d_ws;
    ee = xx + N_ROWS;
    rmin = ee + N_TOK;
    ridx = (int*)(rmin + (size_t)N_ROWS * N_SAMP);
    E = (float*)(ridx + (size_t)N_ROWS * N_SAMP);
  } else if (fixed_f * 4 <= ws_size) {
    KC = 512;
    xx = (float*)d_ws;
    ee = xx + N_ROWS;
    rmin = ee + N_TOK;
    ridx = (int*)(rmin + (size_t)N_ROWS * N_SAMP);
    E = out_q;
  } else {
    KC = 256;
    E = out_q;
    float* tail = out_q + (out_f - fixed_f);
    xx = tail;
    ee = xx + N_ROWS;
    rmin = ee + N_TOK;
    ridx = (int*)(rmin + (size_t)N_ROWS * N_SAMP);
  }

  rownorm_kernel<<<2048, 256, 0, stream>>>(x, xx);
  rownorm_kernel<<<2048, 256, 0, stream>>>(emb, ee);
  init_state_kernel<<<(N_ROWS * N_SAMP + 255) / 256, 256, 0, stream>>>(rmin, ridx);
  for (int ks = 0; ks < N_TOK; ks += KC) {
    gemm_nt_kernel<<<dim3(KC / 64, N_ROWS / 64), 256, 0, stream>>>(x, emb, xx, ee, E, ks, KC);
    sample_kernel<<<2048, 256, 0, stream>>>(E, rmin, ridx, ks, KC, s0, s1);
  }
  gather_fb_kernel<<<2048, 256, 0, stream>>>(emb, ridx, x, out_q, out_s);
}